// Round 3
// baseline (687.207 us; speedup 1.0000x reference)
//
#include <hip/hip_runtime.h>
#include <hip/hip_bf16.h>
#include <math.h>

// Problem constants
#define BB 2
#define NN 4096
#define CC 256
#define HH 8
#define MM 48
#define TT 10000
#define LL 256
#define CHDIM 32
#define HIDD 512
#define ROWS (BB*NN)   // 8192

// ---------------- pe_table = pre_table @ Wpe + bpe  (T x H) ----------------
__global__ void pe_kernel(const float* __restrict__ pre, const float* __restrict__ Wpe,
                          const float* __restrict__ bpe, float* __restrict__ pet) {
    int i = blockIdx.x * blockDim.x + threadIdx.x;   // t*H + h
    if (i >= TT * HH) return;
    int t = i / HH, h = i % HH;
    float s = bpe[h];
    #pragma unroll
    for (int j = 0; j < 5; ++j) s += pre[t * 5 + j] * Wpe[j * HH + h];
    pet[i] = s;
}

// ---------------- LayerNorm over C=256, one block per row ----------------
__global__ __launch_bounds__(256) void ln_kernel(const float* __restrict__ in,
                                                 const float* __restrict__ g,
                                                 const float* __restrict__ b,
                                                 float* __restrict__ out) {
    int row = blockIdx.x;
    int tid = threadIdx.x;
    float v = in[(size_t)row * CC + tid];
    __shared__ float r1[4], r2[4];
    float s = v;
    #pragma unroll
    for (int off = 32; off; off >>= 1) s += __shfl_xor(s, off, 64);
    if ((tid & 63) == 0) r1[tid >> 6] = s;
    __syncthreads();
    float mu = (r1[0] + r1[1] + r1[2] + r1[3]) * (1.0f / 256.0f);
    float d = v - mu;
    float s2 = d * d;
    #pragma unroll
    for (int off = 32; off; off >>= 1) s2 += __shfl_xor(s2, off, 64);
    if ((tid & 63) == 0) r2[tid >> 6] = s2;
    __syncthreads();
    float var = (r2[0] + r2[1] + r2[2] + r2[3]) * (1.0f / 256.0f);
    float rs = rsqrtf(var + 1e-5f);
    out[(size_t)row * CC + tid] = d * rs * g[tid] + b[tid];
}

// ---------------- fp32 tiled GEMM: out = act((A@W + bias)*scale) + residual ----------------
#define BM 128
#define BN 128
#define BKK 16
__global__ __launch_bounds__(256) void gemm_kernel(const float* __restrict__ A,
                                                   const float* __restrict__ W,
                                                   const float* __restrict__ bias,
                                                   float* __restrict__ out,
                                                   int M, int Nn, int K, float scale,
                                                   const float* __restrict__ residual,
                                                   int act) {
    __shared__ float As[BKK][BM];
    __shared__ float Bs[BKK][BN];
    int tid = threadIdx.x;
    int tx = tid % 16, ty = tid / 16;
    int row0 = blockIdx.y * BM, col0 = blockIdx.x * BN;
    float acc[8][8] = {};
    for (int k0 = 0; k0 < K; k0 += BKK) {
        {
            int m = tid >> 1;
            int kq = (tid & 1) * 8;
            const float* ap = A + (size_t)(row0 + m) * K + k0 + kq;
            float4 a0 = *(const float4*)ap;
            float4 a1 = *(const float4*)(ap + 4);
            As[kq + 0][m] = a0.x; As[kq + 1][m] = a0.y; As[kq + 2][m] = a0.z; As[kq + 3][m] = a0.w;
            As[kq + 4][m] = a1.x; As[kq + 5][m] = a1.y; As[kq + 6][m] = a1.z; As[kq + 7][m] = a1.w;
        }
        {
            int kk = tid >> 4;
            int nq = (tid & 15) * 8;
            const float* bp = W + (size_t)(k0 + kk) * Nn + col0 + nq;
            *(float4*)&Bs[kk][nq]     = *(const float4*)bp;
            *(float4*)&Bs[kk][nq + 4] = *(const float4*)(bp + 4);
        }
        __syncthreads();
        #pragma unroll
        for (int kk = 0; kk < BKK; ++kk) {
            float a[8], bb[8];
            #pragma unroll
            for (int i = 0; i < 8; ++i) a[i] = As[kk][ty * 8 + i];
            #pragma unroll
            for (int j = 0; j < 8; ++j) bb[j] = Bs[kk][tx * 8 + j];
            #pragma unroll
            for (int i = 0; i < 8; ++i)
                #pragma unroll
                for (int j = 0; j < 8; ++j)
                    acc[i][j] += a[i] * bb[j];
        }
        __syncthreads();
    }
    #pragma unroll
    for (int i = 0; i < 8; ++i) {
        size_t r = row0 + ty * 8 + i;
        #pragma unroll
        for (int jj = 0; jj < 2; ++jj) {
            int cbase = col0 + tx * 8 + jj * 4;
            float4 bv = *(const float4*)&bias[cbase];
            float vout[4];
            float bva[4] = {bv.x, bv.y, bv.z, bv.w};
            #pragma unroll
            for (int j = 0; j < 4; ++j) {
                float v = (acc[i][jj * 4 + j] + bva[j]) * scale;
                if (act == 1) v = 0.5f * v * (1.0f + erff(v * 0.70710678118654752f));
                vout[j] = v;
            }
            if (residual) {
                float4 rv = *(const float4*)&residual[r * Nn + cbase];
                vout[0] += rv.x; vout[1] += rv.y; vout[2] += rv.z; vout[3] += rv.w;
            }
            *(float4*)&out[r * Nn + cbase] = make_float4(vout[0], vout[1], vout[2], vout[3]);
        }
    }
}

// ---------------- cluster attention v2.1: one wave per (b,n,h), all-lane PV ----------------
// q: [8192,256] (scaled), kv: [8192,512] col = h*64 + s*32 + ch
__global__ __launch_bounds__(256) void cluster_attn_kernel(
    const float* __restrict__ q, const float* __restrict__ kv,
    const int* __restrict__ member_idx, const int* __restrict__ cluster_mask,
    const int* __restrict__ pe_idx, const float* __restrict__ pet,
    const float* __restrict__ blank_k, const float* __restrict__ blank_v,
    float* __restrict__ outp) {
    __shared__ float s_q[4][32];
    int tid = threadIdx.x;
    int wid = tid >> 6, lane = tid & 63;
    int w = blockIdx.x * 4 + wid;      // (row*8 + h)
    int h = w & 7;
    int row = w >> 3;                  // b*4096 + n
    int b = row >> 12;
    if (lane < 32) s_q[wid][lane] = q[(size_t)row * CC + h * CHDIM + lane];
    __syncthreads();
    const float4* sq4 = (const float4*)s_q[wid];

    int idxreg = 0;
    float e = 0.0f;
    if (lane < MM) {
        idxreg = member_idx[(size_t)row * MM + lane];
        const float4* krow = (const float4*)(kv + ((size_t)(b * NN + idxreg)) * 512 + h * 64);
        float d = 0.0f;
        #pragma unroll
        for (int c8 = 0; c8 < 8; ++c8) {
            float4 kk4 = krow[c8];
            float4 q4 = sq4[c8];
            d += q4.x * kk4.x + q4.y * kk4.y + q4.z * kk4.z + q4.w * kk4.w;
        }
        d += pet[(size_t)pe_idx[(size_t)row * MM + lane] * HH + h];
        if (cluster_mask[(size_t)row * MM + lane] == 0) d -= 100.0f;
        // logits are O(0.3); softmax without max-subtract is safe (exp(-100)->0 matches ref)
        e = expf(d);
    } else if (lane == MM) {
        const float4* bk4 = (const float4*)(blank_k + h * CHDIM);
        float d = 0.0f;
        #pragma unroll
        for (int c8 = 0; c8 < 8; ++c8) {
            float4 kk4 = bk4[c8];
            float4 q4 = sq4[c8];
            d += q4.x * kk4.x + q4.y * kk4.y + q4.z * kk4.z + q4.w * kk4.w;
        }
        e = expf(d);
    }
    float ssum = e;
    #pragma unroll
    for (int off = 32; off; off >>= 1) ssum += __shfl_xor(ssum, off, 64);
    float p = e / ssum;

    // BUGFIX R2: shuffle from lane 48 must happen while ALL lanes are active —
    // ds_bpermute does not source data from exec-masked-off lanes.
    float p48 = __shfl(p, MM, 64);

    // PV: lanes split m-range across wave halves; c = lane&31
    int c = lane & 31, half = lane >> 5;
    const float* vbase = kv + h * 64 + 32 + c;
    float accv = 0.0f;
    int m0 = half * 24;
    #pragma unroll 8
    for (int m = m0; m < m0 + 24; ++m) {
        int im = __shfl(idxreg, m, 64);
        float pm = __shfl(p, m, 64);
        accv += pm * vbase[(size_t)(b * NN + im) * 512];
    }
    accv += __shfl_xor(accv, 32, 64);
    if (lane < 32) {
        accv += p48 * blank_v[h * CHDIM + c];
        outp[(size_t)row * CC + h * CHDIM + c] = accv;
    }
}

// ---------------- cross attention v2: single-pass, no-max softmax, chunked K/V in LDS ----------------
#define QT 64
#define LCH 64
__global__ __launch_bounds__(64) void cross_attn_kernel(
    const float* __restrict__ xq,   // [8192,256] scaled
    const float* __restrict__ xk,   // [512,256]
    const float* __restrict__ xv,   // [512,256]
    float* __restrict__ o) {        // [8192,256]
    __shared__ float4 ks[LCH][8];
    __shared__ float4 vs[LCH][8];
    int tid = threadIdx.x;
    int tile = blockIdx.x, h = blockIdx.y, b = blockIdx.z;
    int n = tile * QT + tid;
    size_t qoff = ((size_t)(b * NN + n)) * CC + h * CHDIM;
    float4 q4[8];
    const float4* qsrc = (const float4*)(xq + qoff);
    #pragma unroll
    for (int c8 = 0; c8 < 8; ++c8) q4[c8] = qsrc[c8];

    float ssum = 0.0f;
    float4 acc[8] = {};
    for (int ch = 0; ch < LL / LCH; ++ch) {
        // stage K/V chunk: 64 rows x 32 floats each
        for (int i = tid; i < LCH * 8; i += QT) {
            int l = i >> 3;
            int c4 = i & 7;
            size_t goff = ((size_t)(b * LL + ch * LCH + l)) * CC + h * CHDIM + c4 * 4;
            ks[l][c4] = *(const float4*)&xk[goff];
            vs[l][c4] = *(const float4*)&xv[goff];
        }
        __syncthreads();
        #pragma unroll 2
        for (int l = 0; l < LCH; ++l) {
            float d = 0.0f;
            #pragma unroll
            for (int c8 = 0; c8 < 8; ++c8) {
                float4 kk4 = ks[l][c8];
                d += q4[c8].x * kk4.x + q4[c8].y * kk4.y + q4[c8].z * kk4.z + q4[c8].w * kk4.w;
            }
            // logits are O(0.1) std; exp without max-subtract cannot overflow
            float e = expf(d);
            ssum += e;
            #pragma unroll
            for (int c8 = 0; c8 < 8; ++c8) {
                float4 vv4 = vs[l][c8];
                acc[c8].x += e * vv4.x; acc[c8].y += e * vv4.y;
                acc[c8].z += e * vv4.z; acc[c8].w += e * vv4.w;
            }
        }
        __syncthreads();
    }
    float inv = 1.0f / ssum;
    float4* dst = (float4*)(o + qoff);
    #pragma unroll
    for (int c8 = 0; c8 < 8; ++c8) {
        dst[c8] = make_float4(acc[c8].x * inv, acc[c8].y * inv, acc[c8].z * inv, acc[c8].w * inv);
    }
}

extern "C" void kernel_launch(void* const* d_in, const int* in_sizes, int n_in,
                              void* d_out, int out_size, void* d_ws, size_t ws_size,
                              hipStream_t stream) {
    const float* feat        = (const float*)d_in[0];
    const float* memory      = (const float*)d_in[1];
    const int*   member_idx  = (const int*)d_in[2];
    const int*   cluster_mask= (const int*)d_in[3];
    const int*   pe_idx      = (const int*)d_in[4];
    // d_in[5] global_attn == 0 (asserted in reference)
    const float* pre_table   = (const float*)d_in[6];
    const float* Wq    = (const float*)d_in[7];
    const float* bq    = (const float*)d_in[8];
    const float* Wkv   = (const float*)d_in[9];
    const float* bkv   = (const float*)d_in[10];
    const float* blank_k = (const float*)d_in[11];
    const float* blank_v = (const float*)d_in[12];
    const float* Wpe   = (const float*)d_in[13];
    const float* bpe   = (const float*)d_in[14];
    const float* Wproj = (const float*)d_in[15];
    const float* bproj = (const float*)d_in[16];
    const float* g1    = (const float*)d_in[17];
    const float* be1   = (const float*)d_in[18];
    const float* g2    = (const float*)d_in[19];
    const float* be2   = (const float*)d_in[20];
    const float* xWq   = (const float*)d_in[21];
    const float* xbq   = (const float*)d_in[22];
    const float* xWk   = (const float*)d_in[23];
    const float* xbk   = (const float*)d_in[24];
    const float* xWv   = (const float*)d_in[25];
    const float* xbv   = (const float*)d_in[26];
    const float* xWo   = (const float*)d_in[27];
    const float* xbo   = (const float*)d_in[28];
    const float* xg    = (const float*)d_in[29];
    const float* xbe   = (const float*)d_in[30];
    const float* W1    = (const float*)d_in[31];
    const float* bf1   = (const float*)d_in[32];
    const float* W2    = (const float*)d_in[33];
    const float* bf2   = (const float*)d_in[34];
    float* out = (float*)d_out;
    float* ws  = (float*)d_ws;

    float* bufA = ws;                  // 2M  (x1 / t2 / t3)
    float* bufB = ws + 2097152;        // 2M  (q / xq)
    float* bufC = ws + 4194304;        // 4M  (kv / hidden)
    float* bufD = ws + 8388608;        // 2M  (attnout / o)
    float* bufE = ws + 10485760;       // 2M  (feat1)
    float* xk   = ws + 12582912;       // 131072
    float* xv   = xk + 131072;         // 131072
    float* pet  = xv + 131072;         // 80000

    const float scale = 0.17677669529663689f; // 1/sqrt(32)

    pe_kernel<<<(TT * HH + 255) / 256, 256, 0, stream>>>(pre_table, Wpe, bpe, pet);
    ln_kernel<<<ROWS, 256, 0, stream>>>(feat, g1, be1, bufA);
    gemm_kernel<<<dim3(CC / BN, ROWS / BM), 256, 0, stream>>>(bufA, Wq, bq, bufB, ROWS, CC, CC, scale, nullptr, 0);
    gemm_kernel<<<dim3(512 / BN, ROWS / BM), 256, 0, stream>>>(bufA, Wkv, bkv, bufC, ROWS, 512, CC, 1.0f, nullptr, 0);
    cluster_attn_kernel<<<ROWS * HH / 4, 256, 0, stream>>>(bufB, bufC, member_idx, cluster_mask, pe_idx, pet, blank_k, blank_v, bufD);
    gemm_kernel<<<dim3(CC / BN, ROWS / BM), 256, 0, stream>>>(bufD, Wproj, bproj, bufE, ROWS, CC, CC, 1.0f, feat, 0);
    ln_kernel<<<ROWS, 256, 0, stream>>>(bufE, xg, xbe, bufA);
    gemm_kernel<<<dim3(CC / BN, ROWS / BM), 256, 0, stream>>>(bufA, xWq, xbq, bufB, ROWS, CC, CC, scale, nullptr, 0);
    gemm_kernel<<<dim3(CC / BN, (BB * LL) / BM), 256, 0, stream>>>(memory, xWk, xbk, xk, BB * LL, CC, CC, 1.0f, nullptr, 0);
    gemm_kernel<<<dim3(CC / BN, (BB * LL) / BM), 256, 0, stream>>>(memory, xWv, xbv, xv, BB * LL, CC, CC, 1.0f, nullptr, 0);
    cross_attn_kernel<<<dim3(NN / QT, HH, BB), 64, 0, stream>>>(bufB, xk, xv, bufD);
    gemm_kernel<<<dim3(CC / BN, ROWS / BM), 256, 0, stream>>>(bufD, xWo, xbo, out, ROWS, CC, CC, 1.0f, bufE, 0);
    ln_kernel<<<ROWS, 256, 0, stream>>>(out, g2, be2, bufA);
    gemm_kernel<<<dim3(HIDD / BN, ROWS / BM), 256, 0, stream>>>(bufA, W1, bf1, bufC, ROWS, HIDD, CC, 1.0f, nullptr, 1);
    gemm_kernel<<<dim3(CC / BN, ROWS / BM), 256, 0, stream>>>(bufC, W2, bf2, out, ROWS, CC, HIDD, 1.0f, out, 0);
}

// Round 4
// 334.318 us; speedup vs baseline: 2.0555x; 2.0555x over previous
//
#include <hip/hip_runtime.h>
#include <hip/hip_bf16.h>
#include <math.h>

// Problem constants
#define BB 2
#define NN 4096
#define CC 256
#define HH 8
#define MM 48
#define TT 10000
#define LL 256
#define CHDIM 32
#define HIDD 512
#define ROWS (BB*NN)   // 8192

typedef __attribute__((ext_vector_type(8))) short bf16x8;
typedef __attribute__((ext_vector_type(4))) float f32x4;

// ---------------- pe_table = pre_table @ Wpe + bpe  (T x H) ----------------
__global__ void pe_kernel(const float* __restrict__ pre, const float* __restrict__ Wpe,
                          const float* __restrict__ bpe, float* __restrict__ pet) {
    int i = blockIdx.x * blockDim.x + threadIdx.x;   // t*H + h
    if (i >= TT * HH) return;
    int t = i / HH, h = i % HH;
    float s = bpe[h];
    #pragma unroll
    for (int j = 0; j < 5; ++j) s += pre[t * 5 + j] * Wpe[j * HH + h];
    pet[i] = s;
}

// ---------------- fused weight transpose+convert: dst[N][K] bf16 = src[K][N]*scl ----------------
struct WtDesc { const float* src; __hip_bfloat16* dst; int K; int N; int tile0; float scl; };
struct WtArgs { WtDesc d[9]; };
__global__ __launch_bounds__(256) void wtrans_kernel(WtArgs a) {
    __shared__ float tile[32][33];
    int bid = blockIdx.x;
    int mi = 0;
    #pragma unroll
    for (int i = 1; i < 9; ++i) if (bid >= a.d[i].tile0) mi = i;
    WtDesc dsc = a.d[mi];
    int t = bid - dsc.tile0;
    int tiles_n = dsc.N >> 5;
    int k0 = (t / tiles_n) * 32, n0 = (t % tiles_n) * 32;
    int tx = threadIdx.x & 31, ty = threadIdx.x >> 5;   // 32x8
    #pragma unroll
    for (int i = 0; i < 32; i += 8)
        tile[ty + i][tx] = dsc.src[(size_t)(k0 + ty + i) * dsc.N + n0 + tx];
    __syncthreads();
    #pragma unroll
    for (int i = 0; i < 32; i += 8)
        dsc.dst[(size_t)(n0 + ty + i) * dsc.K + k0 + tx] = __float2bfloat16(tile[tx][ty + i] * dsc.scl);
}

// ---------------- bias concat/scale prep ----------------
__global__ void bias_prep_kernel(const float* __restrict__ bq, const float* __restrict__ bkv,
                                 const float* __restrict__ xbk, const float* __restrict__ xbv,
                                 const float* __restrict__ xbq, float scale,
                                 float* __restrict__ bqkv, float* __restrict__ xbkv,
                                 float* __restrict__ xbqS) {
    int i = blockIdx.x * 256 + threadIdx.x;
    if (i < 256) bqkv[i] = bq[i] * scale;
    else if (i < 768) bqkv[i] = bkv[i - 256];
    else if (i < 1024) xbkv[i - 768] = xbk[i - 768];
    else if (i < 1280) xbkv[256 + i - 1024] = xbv[i - 1024];
    else if (i < 1536) xbqS[i - 1280] = xbq[i - 1280] * scale;
}

// ---------------- fp32 -> bf16 convert ----------------
__global__ void cvt_bf16_kernel(const float* __restrict__ src, __hip_bfloat16* __restrict__ dst, int n) {
    int i = blockIdx.x * 256 + threadIdx.x;
    if (i < n) dst[i] = __float2bfloat16(src[i]);
}

// ---------------- LayerNorm over C=256, one block per row, bf16 out ----------------
__global__ __launch_bounds__(256) void ln_kernel(const float* __restrict__ in,
                                                 const float* __restrict__ g,
                                                 const float* __restrict__ b,
                                                 __hip_bfloat16* __restrict__ out) {
    int row = blockIdx.x;
    int tid = threadIdx.x;
    float v = in[(size_t)row * CC + tid];
    __shared__ float r1[4], r2[4];
    float s = v;
    #pragma unroll
    for (int off = 32; off; off >>= 1) s += __shfl_xor(s, off, 64);
    if ((tid & 63) == 0) r1[tid >> 6] = s;
    __syncthreads();
    float mu = (r1[0] + r1[1] + r1[2] + r1[3]) * (1.0f / 256.0f);
    float d = v - mu;
    float s2 = d * d;
    #pragma unroll
    for (int off = 32; off; off >>= 1) s2 += __shfl_xor(s2, off, 64);
    if ((tid & 63) == 0) r2[tid >> 6] = s2;
    __syncthreads();
    float var = (r2[0] + r2[1] + r2[2] + r2[3]) * (1.0f / 256.0f);
    float rs = rsqrtf(var + 1e-5f);
    out[(size_t)row * CC + tid] = __float2bfloat16(d * rs * g[tid] + b[tid]);
}

// ---------------- MFMA bf16 GEMM: out = act(A@B^T + bias) + residual ----------------
// A [M][K] bf16, BT [N][K] bf16, bias [N] f32. BM=128 BN=64 BK=64, 4 waves each own 64x32.
#define GBM 128
#define GBN 64
#define GBK 64
#define LDA 72   // 64 + 8 pad (bf16 units); row stride 144B, 16B-aligned
template<int ACT, int OUTBF>
__global__ __launch_bounds__(256) void mfma_gemm_kernel(
    const __hip_bfloat16* __restrict__ A,
    const __hip_bfloat16* __restrict__ BT,
    const float* __restrict__ bias,
    void* __restrict__ outv,
    const float* __restrict__ residual,
    int M, int N, int K) {
    __shared__ short As[GBM * LDA];
    __shared__ short Bs[GBN * LDA];
    int tid = threadIdx.x;
    int lane = tid & 63, wid = tid >> 6;
    int wr = wid >> 1, wc = wid & 1;
    int row0 = blockIdx.y * GBM, col0 = blockIdx.x * GBN;
    int lr = lane & 15, lk = lane >> 4;
    f32x4 acc[4][2] = {};
    for (int kt = 0; kt < K; kt += GBK) {
        #pragma unroll
        for (int i = 0; i < 4; ++i) {
            int flat = tid + i * 256;
            int r = flat >> 3, kc = (flat & 7) * 8;
            *(bf16x8*)&As[r * LDA + kc] = *(const bf16x8*)(A + (size_t)(row0 + r) * K + kt + kc);
        }
        #pragma unroll
        for (int i = 0; i < 2; ++i) {
            int flat = tid + i * 256;
            int r = flat >> 3, kc = (flat & 7) * 8;
            *(bf16x8*)&Bs[r * LDA + kc] = *(const bf16x8*)(BT + (size_t)(col0 + r) * K + kt + kc);
        }
        __syncthreads();
        #pragma unroll
        for (int ks = 0; ks < 2; ++ks) {
            bf16x8 bfr[2];
            #pragma unroll
            for (int n = 0; n < 2; ++n)
                bfr[n] = *(const bf16x8*)&Bs[(wc * 32 + n * 16 + lr) * LDA + ks * 32 + lk * 8];
            #pragma unroll
            for (int m = 0; m < 4; ++m) {
                bf16x8 afr = *(const bf16x8*)&As[(wr * 64 + m * 16 + lr) * LDA + ks * 32 + lk * 8];
                #pragma unroll
                for (int n = 0; n < 2; ++n)
                    acc[m][n] = __builtin_amdgcn_mfma_f32_16x16x32_bf16(afr, bfr[n], acc[m][n], 0, 0, 0);
            }
        }
        __syncthreads();
    }
    // epilogue: D layout col=lane&15, row=(lane>>4)*4+reg (m89-verified)
    float bv[2];
    #pragma unroll
    for (int n = 0; n < 2; ++n) bv[n] = bias[col0 + wc * 32 + n * 16 + lr];
    #pragma unroll
    for (int m = 0; m < 4; ++m) {
        #pragma unroll
        for (int n = 0; n < 2; ++n) {
            int col = col0 + wc * 32 + n * 16 + lr;
            #pragma unroll
            for (int r = 0; r < 4; ++r) {
                int row = row0 + wr * 64 + m * 16 + lk * 4 + r;
                float v = acc[m][n][r] + bv[n];
                if (ACT == 1) v = 0.5f * v * (1.0f + erff(v * 0.70710678118654752f));
                size_t oi = (size_t)row * N + col;
                if (residual) v += residual[oi];
                if (OUTBF) ((__hip_bfloat16*)outv)[oi] = __float2bfloat16(v);
                else ((float*)outv)[oi] = v;
            }
        }
    }
}

// ---------------- cluster attention: one wave per (b,n,h), reads fused qkv [8192][768] ----------------
__global__ __launch_bounds__(256) void cluster_attn_kernel(
    const float* __restrict__ qkv,
    const int* __restrict__ member_idx, const int* __restrict__ cluster_mask,
    const int* __restrict__ pe_idx, const float* __restrict__ pet,
    const float* __restrict__ blank_k, const float* __restrict__ blank_v,
    __hip_bfloat16* __restrict__ outp) {
    __shared__ float s_q[4][32];
    int tid = threadIdx.x;
    int wid = tid >> 6, lane = tid & 63;
    int w = blockIdx.x * 4 + wid;      // (row*8 + h)
    int h = w & 7;
    int row = w >> 3;                  // b*4096 + n
    int b = row >> 12;
    if (lane < 32) s_q[wid][lane] = qkv[(size_t)row * 768 + h * CHDIM + lane];
    __syncthreads();
    const float4* sq4 = (const float4*)s_q[wid];

    int idxreg = 0;
    float e = 0.0f;
    if (lane < MM) {
        idxreg = member_idx[(size_t)row * MM + lane];
        const float4* krow = (const float4*)(qkv + ((size_t)(b * NN + idxreg)) * 768 + 256 + h * 64);
        float d = 0.0f;
        #pragma unroll
        for (int c8 = 0; c8 < 8; ++c8) {
            float4 kk4 = krow[c8];
            float4 q4 = sq4[c8];
            d += q4.x * kk4.x + q4.y * kk4.y + q4.z * kk4.z + q4.w * kk4.w;
        }
        d += pet[(size_t)pe_idx[(size_t)row * MM + lane] * HH + h];
        if (cluster_mask[(size_t)row * MM + lane] == 0) d -= 100.0f;
        e = expf(d);   // logits O(1); no-max softmax exact enough, exp(-100)->0
    } else if (lane == MM) {
        const float4* bk4 = (const float4*)(blank_k + h * CHDIM);
        float d = 0.0f;
        #pragma unroll
        for (int c8 = 0; c8 < 8; ++c8) {
            float4 kk4 = bk4[c8];
            float4 q4 = sq4[c8];
            d += q4.x * kk4.x + q4.y * kk4.y + q4.z * kk4.z + q4.w * kk4.w;
        }
        e = expf(d);
    }
    float ssum = e;
    #pragma unroll
    for (int off = 32; off; off >>= 1) ssum += __shfl_xor(ssum, off, 64);
    float p = e / ssum;
    float p48 = __shfl(p, MM, 64);   // while all lanes active

    int c = lane & 31, half = lane >> 5;
    const float* vbase = qkv + 256 + h * 64 + 32 + c;
    float accv = 0.0f;
    int m0 = half * 24;
    #pragma unroll 8
    for (int m = m0; m < m0 + 24; ++m) {
        int im = __shfl(idxreg, m, 64);
        float pm = __shfl(p, m, 64);
        accv += pm * vbase[(size_t)(b * NN + im) * 768];
    }
    accv += __shfl_xor(accv, 32, 64);
    if (lane < 32) {
        accv += p48 * blank_v[h * CHDIM + c];
        outp[(size_t)row * CC + h * CHDIM + c] = __float2bfloat16(accv);
    }
}

// ---------------- cross attention v3: 4 waves split L, LDS combine ----------------
#define XQT 64
__global__ __launch_bounds__(256) void cross_attn_kernel(
    const float* __restrict__ xq,    // [8192][256] scaled
    const float* __restrict__ xkv,   // [512][512]: k at col h*32+c, v at 256+h*32+c
    __hip_bfloat16* __restrict__ o) {
    __shared__ float sacc[4][XQT][33];
    __shared__ float ssums[4][XQT];
    int tid = threadIdx.x, lane = tid & 63, w = tid >> 6;
    int tile = blockIdx.x, h = blockIdx.y, b = blockIdx.z;
    int n = tile * XQT + lane;
    const float* qp = xq + (size_t)(b * NN + n) * CC + h * CHDIM;
    float q[32];
    #pragma unroll
    for (int i = 0; i < 8; ++i) *(float4*)&q[i * 4] = ((const float4*)qp)[i];
    float ssum = 0.0f, acc[32] = {};
    const float* kbase = xkv + (size_t)(b * LL + w * 64) * 512 + h * CHDIM;   // wave-uniform
    for (int l = 0; l < 64; ++l) {
        const float* kr = kbase + (size_t)l * 512;
        float d0 = 0.f, d1 = 0.f, d2 = 0.f, d3 = 0.f;
        #pragma unroll
        for (int c4 = 0; c4 < 8; ++c4) {
            float4 kk = *(const float4*)&kr[c4 * 4];
            d0 += q[c4 * 4 + 0] * kk.x; d1 += q[c4 * 4 + 1] * kk.y;
            d2 += q[c4 * 4 + 2] * kk.z; d3 += q[c4 * 4 + 3] * kk.w;
        }
        float e = __expf((d0 + d1) + (d2 + d3));
        ssum += e;
        #pragma unroll
        for (int c4 = 0; c4 < 8; ++c4) {
            float4 vv = *(const float4*)&kr[256 + c4 * 4];
            acc[c4 * 4 + 0] += e * vv.x; acc[c4 * 4 + 1] += e * vv.y;
            acc[c4 * 4 + 2] += e * vv.z; acc[c4 * 4 + 3] += e * vv.w;
        }
    }
    ssums[w][lane] = ssum;
    #pragma unroll
    for (int c = 0; c < 32; ++c) sacc[w][lane][c] = acc[c];
    __syncthreads();
    int qi = tid >> 2, part = tid & 3;
    float st = ssums[0][qi] + ssums[1][qi] + ssums[2][qi] + ssums[3][qi];
    float inv = 1.0f / st;
    int n2 = tile * XQT + qi;
    __hip_bfloat16* op = o + (size_t)(b * NN + n2) * CC + h * CHDIM + part * 8;
    #pragma unroll
    for (int cc = 0; cc < 8; ++cc) {
        int c = part * 8 + cc;
        float v = sacc[0][qi][c] + sacc[1][qi][c] + sacc[2][qi][c] + sacc[3][qi][c];
        op[cc] = __float2bfloat16(v * inv);
    }
}

extern "C" void kernel_launch(void* const* d_in, const int* in_sizes, int n_in,
                              void* d_out, int out_size, void* d_ws, size_t ws_size,
                              hipStream_t stream) {
    const float* feat        = (const float*)d_in[0];
    const float* memory      = (const float*)d_in[1];
    const int*   member_idx  = (const int*)d_in[2];
    const int*   cluster_mask= (const int*)d_in[3];
    const int*   pe_idx      = (const int*)d_in[4];
    const float* pre_table   = (const float*)d_in[6];
    const float* Wq    = (const float*)d_in[7];
    const float* bq    = (const float*)d_in[8];
    const float* Wkv   = (const float*)d_in[9];
    const float* bkv   = (const float*)d_in[10];
    const float* blank_k = (const float*)d_in[11];
    const float* blank_v = (const float*)d_in[12];
    const float* Wpe   = (const float*)d_in[13];
    const float* bpe   = (const float*)d_in[14];
    const float* Wproj = (const float*)d_in[15];
    const float* bproj = (const float*)d_in[16];
    const float* g1    = (const float*)d_in[17];
    const float* be1   = (const float*)d_in[18];
    const float* g2    = (const float*)d_in[19];
    const float* be2   = (const float*)d_in[20];
    const float* xWq   = (const float*)d_in[21];
    const float* xbq   = (const float*)d_in[22];
    const float* xWk   = (const float*)d_in[23];
    const float* xbk   = (const float*)d_in[24];
    const float* xWv   = (const float*)d_in[25];
    const float* xbv   = (const float*)d_in[26];
    const float* xWo   = (const float*)d_in[27];
    const float* xbo   = (const float*)d_in[28];
    const float* xg    = (const float*)d_in[29];
    const float* xbe   = (const float*)d_in[30];
    const float* W1    = (const float*)d_in[31];
    const float* bf1   = (const float*)d_in[32];
    const float* W2    = (const float*)d_in[33];
    const float* bf2   = (const float*)d_in[34];
    float* out = (float*)d_out;
    float* ws  = (float*)d_ws;

    // workspace layout (float units)
    float* qkvF  = ws;                         // [8192][768] f32 (dead after cluster_attn)
    float* xqF   = ws;                         // alias: [8192][256] f32
    float* xkvF  = ws + 2097152;               // [512][512] f32
    __hip_bfloat16* hBf  = (__hip_bfloat16*)(ws + 2359296);   // [8192][512] bf16
    float* feat1F = ws + 6291456;              // [8192][256] f32
    __hip_bfloat16* aBf  = (__hip_bfloat16*)(ws + 8388608);   // [8192][256] bf16 (LN outs)
    __hip_bfloat16* oBf  = (__hip_bfloat16*)(ws + 9437184);   // [8192][256] bf16 (attn outs)
    __hip_bfloat16* WqkvT = (__hip_bfloat16*)(ws + 10485760); // [768][256]
    __hip_bfloat16* WprojT= (__hip_bfloat16*)(ws + 10584064); // [256][256]
    __hip_bfloat16* xWqT  = (__hip_bfloat16*)(ws + 10616832);
    __hip_bfloat16* xWoT  = (__hip_bfloat16*)(ws + 10649600);
    __hip_bfloat16* xWkvT = (__hip_bfloat16*)(ws + 10682368); // [512][256]
    __hip_bfloat16* W1T   = (__hip_bfloat16*)(ws + 10747904); // [512][256]
    __hip_bfloat16* W2T   = (__hip_bfloat16*)(ws + 10813440); // [256][512]
    __hip_bfloat16* memBf = (__hip_bfloat16*)(ws + 10878976); // [512][256]
    float* pet   = ws + 10944512;              // 80000
    float* bqkv  = ws + 11024512;              // 768
    float* xbkv  = ws + 11025280;              // 512
    float* xbqS  = ws + 11025792;              // 256

    const float scale = 0.17677669529663689f; // 1/sqrt(32)

    // ---- prep ----
    pe_kernel<<<(TT * HH + 255) / 256, 256, 0, stream>>>(pre_table, Wpe, bpe, pet);
    WtArgs wa;
    wa.d[0] = { Wq,    WqkvT,          256, 256, 0,   scale };
    wa.d[1] = { Wkv,   WqkvT + 65536,  256, 512, 64,  1.0f };
    wa.d[2] = { Wproj, WprojT,         256, 256, 192, 1.0f };
    wa.d[3] = { xWq,   xWqT,           256, 256, 256, scale };
    wa.d[4] = { xWk,   xWkvT,          256, 256, 320, 1.0f };
    wa.d[5] = { xWv,   xWkvT + 65536,  256, 256, 384, 1.0f };
    wa.d[6] = { xWo,   xWoT,           256, 256, 448, 1.0f };
    wa.d[7] = { W1,    W1T,            256, 512, 512, 1.0f };
    wa.d[8] = { W2,    W2T,            512, 256, 640, 1.0f };
    wtrans_kernel<<<768, 256, 0, stream>>>(wa);
    bias_prep_kernel<<<6, 256, 0, stream>>>(bq, bkv, xbk, xbv, xbq, scale, bqkv, xbkv, xbqS);
    cvt_bf16_kernel<<<512, 256, 0, stream>>>(memory, memBf, 131072);

    // ---- block ----
    ln_kernel<<<ROWS, 256, 0, stream>>>(feat, g1, be1, aBf);
    mfma_gemm_kernel<0,0><<<dim3(12, 64), 256, 0, stream>>>(aBf, WqkvT, bqkv, qkvF, nullptr, ROWS, 768, 256);
    cluster_attn_kernel<<<ROWS * HH / 4, 256, 0, stream>>>(qkvF, member_idx, cluster_mask, pe_idx, pet, blank_k, blank_v, oBf);
    mfma_gemm_kernel<0,0><<<dim3(4, 64), 256, 0, stream>>>(oBf, WprojT, bproj, feat1F, feat, ROWS, 256, 256);
    ln_kernel<<<ROWS, 256, 0, stream>>>(feat1F, xg, xbe, aBf);
    mfma_gemm_kernel<0,0><<<dim3(4, 64), 256, 0, stream>>>(aBf, xWqT, xbqS, xqF, nullptr, ROWS, 256, 256);
    mfma_gemm_kernel<0,0><<<dim3(8, 4), 256, 0, stream>>>(memBf, xWkvT, xbkv, xkvF, nullptr, 512, 512, 256);
    cross_attn_kernel<<<dim3(NN / XQT, HH, BB), 256, 0, stream>>>(xqF, xkvF, oBf);
    mfma_gemm_kernel<0,0><<<dim3(4, 64), 256, 0, stream>>>(oBf, xWoT, xbo, out, feat1F, ROWS, 256, 256);
    ln_kernel<<<ROWS, 256, 0, stream>>>(out, g2, be2, aBf);
    mfma_gemm_kernel<1,1><<<dim3(8, 64), 256, 0, stream>>>(aBf, W1T, bf1, hBf, nullptr, ROWS, HIDD, 256);
    mfma_gemm_kernel<0,0><<<dim3(4, 64), 256, 0, stream>>>(hBf, W2T, bf2, out, out, ROWS, 256, HIDD);
}

// Round 5
// 218.837 us; speedup vs baseline: 3.1403x; 1.5277x over previous
//
#include <hip/hip_runtime.h>
#include <hip/hip_bf16.h>
#include <math.h>

// Problem constants
#define BB 2
#define NN 4096
#define CC 256
#define HH 8
#define MM 48
#define TT 10000
#define LL 256
#define CHDIM 32
#define HIDD 512
#define ROWS (BB*NN)   // 8192

typedef __attribute__((ext_vector_type(8))) short bf16x8;
typedef __attribute__((ext_vector_type(4))) float f32x4;

static __device__ __forceinline__ short f2bf(float x) {
    __hip_bfloat16 h = __float2bfloat16(x);
    return *reinterpret_cast<short*>(&h);
}

// ---------------- pe_table = pre_table @ Wpe + bpe  (T x H) ----------------
__global__ void pe_kernel(const float* __restrict__ pre, const float* __restrict__ Wpe,
                          const float* __restrict__ bpe, float* __restrict__ pet) {
    int i = blockIdx.x * blockDim.x + threadIdx.x;   // t*H + h
    if (i >= TT * HH) return;
    int t = i / HH, h = i % HH;
    float s = bpe[h];
    #pragma unroll
    for (int j = 0; j < 5; ++j) s += pre[t * 5 + j] * Wpe[j * HH + h];
    pet[i] = s;
}

// ---------------- fused weight transpose+convert: dst[N][K] bf16 = src[K][N]*scl ----------------
struct WtDesc { const float* src; __hip_bfloat16* dst; int K; int N; int tile0; float scl; };
struct WtArgs { WtDesc d[9]; };
__global__ __launch_bounds__(256) void wtrans_kernel(WtArgs a) {
    __shared__ float tile[32][33];
    int bid = blockIdx.x;
    int mi = 0;
    #pragma unroll
    for (int i = 1; i < 9; ++i) if (bid >= a.d[i].tile0) mi = i;
    WtDesc dsc = a.d[mi];
    int t = bid - dsc.tile0;
    int tiles_n = dsc.N >> 5;
    int k0 = (t / tiles_n) * 32, n0 = (t % tiles_n) * 32;
    int tx = threadIdx.x & 31, ty = threadIdx.x >> 5;   // 32x8
    #pragma unroll
    for (int i = 0; i < 32; i += 8)
        tile[ty + i][tx] = dsc.src[(size_t)(k0 + ty + i) * dsc.N + n0 + tx];
    __syncthreads();
    #pragma unroll
    for (int i = 0; i < 32; i += 8)
        dsc.dst[(size_t)(n0 + ty + i) * dsc.K + k0 + tx] = __float2bfloat16(tile[tx][ty + i] * dsc.scl);
}

// ---------------- bias concat/scale prep ----------------
__global__ void bias_prep_kernel(const float* __restrict__ bq, const float* __restrict__ bkv,
                                 const float* __restrict__ xbk, const float* __restrict__ xbv,
                                 const float* __restrict__ xbq, float scale,
                                 float* __restrict__ bqkv, float* __restrict__ xbkv,
                                 float* __restrict__ xbqS) {
    int i = blockIdx.x * 256 + threadIdx.x;
    if (i < 256) bqkv[i] = bq[i] * scale;
    else if (i < 768) bqkv[i] = bkv[i - 256];
    else if (i < 1024) xbkv[i - 768] = xbk[i - 768];
    else if (i < 1280) xbkv[256 + i - 1024] = xbv[i - 1024];
    else if (i < 1536) xbqS[i - 1280] = xbq[i - 1280] * scale;
}

// ---------------- fp32 -> bf16 convert ----------------
__global__ void cvt_bf16_kernel(const float* __restrict__ src, __hip_bfloat16* __restrict__ dst, int n) {
    int i = blockIdx.x * 256 + threadIdx.x;
    if (i < n) dst[i] = __float2bfloat16(src[i]);
}

// ---------------- LayerNorm over C=256, one block per row, bf16 out ----------------
__global__ __launch_bounds__(256) void ln_kernel(const float* __restrict__ in,
                                                 const float* __restrict__ g,
                                                 const float* __restrict__ b,
                                                 __hip_bfloat16* __restrict__ out) {
    int row = blockIdx.x;
    int tid = threadIdx.x;
    float v = in[(size_t)row * CC + tid];
    __shared__ float r1[4], r2[4];
    float s = v;
    #pragma unroll
    for (int off = 32; off; off >>= 1) s += __shfl_xor(s, off, 64);
    if ((tid & 63) == 0) r1[tid >> 6] = s;
    __syncthreads();
    float mu = (r1[0] + r1[1] + r1[2] + r1[3]) * (1.0f / 256.0f);
    float d = v - mu;
    float s2 = d * d;
    #pragma unroll
    for (int off = 32; off; off >>= 1) s2 += __shfl_xor(s2, off, 64);
    if ((tid & 63) == 0) r2[tid >> 6] = s2;
    __syncthreads();
    float var = (r2[0] + r2[1] + r2[2] + r2[3]) * (1.0f / 256.0f);
    float rs = rsqrtf(var + 1e-5f);
    out[(size_t)row * CC + tid] = __float2bfloat16(d * rs * g[tid] + b[tid]);
}

// ---------------- MFMA bf16 GEMM: out = act(A@B^T + bias) + residual ----------------
#define GBM 128
#define GBN 64
#define GBK 64
#define LDA 72   // 64 + 8 pad (bf16 units)
template<int ACT, int OUTBF>
__global__ __launch_bounds__(256) void mfma_gemm_kernel(
    const __hip_bfloat16* __restrict__ A,
    const __hip_bfloat16* __restrict__ BT,
    const float* __restrict__ bias,
    void* __restrict__ outv,
    const float* __restrict__ residual,
    int M, int N, int K) {
    __shared__ short As[GBM * LDA];
    __shared__ short Bs[GBN * LDA];
    int tid = threadIdx.x;
    int lane = tid & 63, wid = tid >> 6;
    int wr = wid >> 1, wc = wid & 1;
    int row0 = blockIdx.y * GBM, col0 = blockIdx.x * GBN;
    int lr = lane & 15, lk = lane >> 4;
    f32x4 acc[4][2] = {};
    for (int kt = 0; kt < K; kt += GBK) {
        #pragma unroll
        for (int i = 0; i < 4; ++i) {
            int flat = tid + i * 256;
            int r = flat >> 3, kc = (flat & 7) * 8;
            *(bf16x8*)&As[r * LDA + kc] = *(const bf16x8*)(A + (size_t)(row0 + r) * K + kt + kc);
        }
        #pragma unroll
        for (int i = 0; i < 2; ++i) {
            int flat = tid + i * 256;
            int r = flat >> 3, kc = (flat & 7) * 8;
            *(bf16x8*)&Bs[r * LDA + kc] = *(const bf16x8*)(BT + (size_t)(col0 + r) * K + kt + kc);
        }
        __syncthreads();
        #pragma unroll
        for (int ks = 0; ks < 2; ++ks) {
            bf16x8 bfr[2];
            #pragma unroll
            for (int n = 0; n < 2; ++n)
                bfr[n] = *(const bf16x8*)&Bs[(wc * 32 + n * 16 + lr) * LDA + ks * 32 + lk * 8];
            #pragma unroll
            for (int m = 0; m < 4; ++m) {
                bf16x8 afr = *(const bf16x8*)&As[(wr * 64 + m * 16 + lr) * LDA + ks * 32 + lk * 8];
                #pragma unroll
                for (int n = 0; n < 2; ++n)
                    acc[m][n] = __builtin_amdgcn_mfma_f32_16x16x32_bf16(afr, bfr[n], acc[m][n], 0, 0, 0);
            }
        }
        __syncthreads();
    }
    float bv[2];
    #pragma unroll
    for (int n = 0; n < 2; ++n) bv[n] = bias[col0 + wc * 32 + n * 16 + lr];
    #pragma unroll
    for (int m = 0; m < 4; ++m) {
        #pragma unroll
        for (int n = 0; n < 2; ++n) {
            int col = col0 + wc * 32 + n * 16 + lr;
            #pragma unroll
            for (int r = 0; r < 4; ++r) {
                int row = row0 + wr * 64 + m * 16 + lk * 4 + r;
                float v = acc[m][n][r] + bv[n];
                if (ACT == 1) v = 0.5f * v * (1.0f + erff(v * 0.70710678118654752f));
                size_t oi = (size_t)row * N + col;
                if (residual) v += residual[oi];
                if (OUTBF) ((__hip_bfloat16*)outv)[oi] = __float2bfloat16(v);
                else ((float*)outv)[oi] = v;
            }
        }
    }
}

// ---------------- cluster attention: one wave per (b,n,h), reads fused qkv [8192][768] ----------------
__global__ __launch_bounds__(256) void cluster_attn_kernel(
    const float* __restrict__ qkv,
    const int* __restrict__ member_idx, const int* __restrict__ cluster_mask,
    const int* __restrict__ pe_idx, const float* __restrict__ pet,
    const float* __restrict__ blank_k, const float* __restrict__ blank_v,
    __hip_bfloat16* __restrict__ outp) {
    __shared__ float s_q[4][32];
    int tid = threadIdx.x;
    int wid = tid >> 6, lane = tid & 63;
    int w = blockIdx.x * 4 + wid;      // (row*8 + h)
    int h = w & 7;
    int row = w >> 3;                  // b*4096 + n
    int b = row >> 12;
    if (lane < 32) s_q[wid][lane] = qkv[(size_t)row * 768 + h * CHDIM + lane];
    __syncthreads();
    const float4* sq4 = (const float4*)s_q[wid];

    int idxreg = 0;
    float e = 0.0f;
    if (lane < MM) {
        idxreg = member_idx[(size_t)row * MM + lane];
        const float4* krow = (const float4*)(qkv + ((size_t)(b * NN + idxreg)) * 768 + 256 + h * 64);
        float d = 0.0f;
        #pragma unroll
        for (int c8 = 0; c8 < 8; ++c8) {
            float4 kk4 = krow[c8];
            float4 q4 = sq4[c8];
            d += q4.x * kk4.x + q4.y * kk4.y + q4.z * kk4.z + q4.w * kk4.w;
        }
        d += pet[(size_t)pe_idx[(size_t)row * MM + lane] * HH + h];
        if (cluster_mask[(size_t)row * MM + lane] == 0) d -= 100.0f;
        e = expf(d);   // logits O(1); no-max softmax, exp(-100)->0
    } else if (lane == MM) {
        const float4* bk4 = (const float4*)(blank_k + h * CHDIM);
        float d = 0.0f;
        #pragma unroll
        for (int c8 = 0; c8 < 8; ++c8) {
            float4 kk4 = bk4[c8];
            float4 q4 = sq4[c8];
            d += q4.x * kk4.x + q4.y * kk4.y + q4.z * kk4.z + q4.w * kk4.w;
        }
        e = expf(d);
    }
    float ssum = e;
    #pragma unroll
    for (int off = 32; off; off >>= 1) ssum += __shfl_xor(ssum, off, 64);
    float p = e / ssum;
    float p48 = __shfl(p, MM, 64);   // while all lanes active

    int c = lane & 31, half = lane >> 5;
    const float* vbase = qkv + 256 + h * 64 + 32 + c;
    float accv = 0.0f;
    int m0 = half * 24;
    #pragma unroll 8
    for (int m = m0; m < m0 + 24; ++m) {
        int im = __shfl(idxreg, m, 64);
        float pm = __shfl(p, m, 64);
        accv += pm * vbase[(size_t)(b * NN + im) * 768];
    }
    accv += __shfl_xor(accv, 32, 64);
    if (lane < 32) {
        accv += p48 * blank_v[h * CHDIM + c];
        outp[(size_t)row * CC + h * CHDIM + c] = __float2bfloat16(accv);
    }
}

// ---------------- cross attention v4: MFMA flash-style ----------------
// Per block: one (b, h), 64 Q rows; 4 waves x 16 rows.
// LDS: Ks [256][40] bf16 (20480B) | Vt [32][264] bf16 (16896B) | Ps [4][16*264] bf16 (33792B)
#define KSLD 40
#define PVLD 264
__global__ __launch_bounds__(256) void cross_attn_kernel(
    const __hip_bfloat16* __restrict__ xq,   // [8192][256] bf16, scaled
    const float* __restrict__ xkv,           // [512][512]: k at col h*32+c, v at 256+h*32+c
    __hip_bfloat16* __restrict__ o) {
    extern __shared__ short lds[];
    short* Ks = lds;                 // 256*40
    short* Vt = lds + 256 * KSLD;    // 32*264
    short* Ps = Vt + 32 * PVLD;      // 4*16*264
    int tid = threadIdx.x, lane = tid & 63, w = tid >> 6;
    int tile = blockIdx.x, h = blockIdx.y, b = blockIdx.z;
    int lr = lane & 15, g = lane >> 4;

    // stage K -> Ks[l][c] bf16, V -> Vt[c][l] bf16 (transposed)
    #pragma unroll
    for (int p = 0; p < 8; ++p) {
        int l = p * 32 + (tid >> 3);
        int c4 = (tid & 7) * 4;
        const float* kvrow = xkv + ((size_t)(b * LL + l)) * 512 + h * CHDIM;
        float4 kk = *(const float4*)(kvrow + c4);
        float4 vv = *(const float4*)(kvrow + 256 + c4);
        union { short s[4]; uint2 u; } pk;
        pk.s[0] = f2bf(kk.x); pk.s[1] = f2bf(kk.y); pk.s[2] = f2bf(kk.z); pk.s[3] = f2bf(kk.w);
        *(uint2*)&Ks[l * KSLD + c4] = pk.u;
        Vt[(c4 + 0) * PVLD + l] = f2bf(vv.x);
        Vt[(c4 + 1) * PVLD + l] = f2bf(vv.y);
        Vt[(c4 + 2) * PVLD + l] = f2bf(vv.z);
        Vt[(c4 + 3) * PVLD + l] = f2bf(vv.w);
    }
    __syncthreads();

    // QK^T: S[16][256] per wave; a-frag row=lr, k=g*8
    int qrow = b * NN + tile * 64 + w * 16 + lr;
    bf16x8 afr = *(const bf16x8*)(xq + (size_t)qrow * CC + h * CHDIM + g * 8);
    f32x4 s[16];
    #pragma unroll
    for (int t = 0; t < 16; ++t) {
        bf16x8 kb = *(const bf16x8*)&Ks[(t * 16 + lr) * KSLD + g * 8];
        s[t] = __builtin_amdgcn_mfma_f32_16x16x32_bf16(afr, kb, (f32x4){0.f,0.f,0.f,0.f}, 0, 0, 0);
    }
    // no-max softmax: exp + row sums (D row = g*4+r, col = t*16+lr)
    float rs[4] = {0.f, 0.f, 0.f, 0.f};
    #pragma unroll
    for (int t = 0; t < 16; ++t)
        #pragma unroll
        for (int r = 0; r < 4; ++r) { float e = __expf(s[t][r]); s[t][r] = e; rs[r] += e; }
    #pragma unroll
    for (int off = 1; off < 16; off <<= 1)
        #pragma unroll
        for (int r = 0; r < 4; ++r) rs[r] += __shfl_xor(rs[r], off, 64);
    // write P (unnormalized) bf16 to per-wave LDS tile: Ps[w][(row)][key]
    short* Pw = Ps + w * 16 * PVLD;
    #pragma unroll
    for (int t = 0; t < 16; ++t)
        #pragma unroll
        for (int r = 0; r < 4; ++r)
            Pw[(g * 4 + r) * PVLD + t * 16 + lr] = f2bf(s[t][r]);
    // PV: out[16][32] = P @ V  (same-wave LDS RAW; compiler inserts lgkmcnt)
    f32x4 oacc[2] = {};
    #pragma unroll
    for (int kc = 0; kc < 8; ++kc) {
        bf16x8 pa = *(const bf16x8*)&Pw[lr * PVLD + kc * 32 + g * 8];
        #pragma unroll
        for (int n = 0; n < 2; ++n) {
            bf16x8 vb = *(const bf16x8*)&Vt[(n * 16 + lr) * PVLD + kc * 32 + g * 8];
            oacc[n] = __builtin_amdgcn_mfma_f32_16x16x32_bf16(pa, vb, oacc[n], 0, 0, 0);
        }
    }
    float inv[4];
    #pragma unroll
    for (int r = 0; r < 4; ++r) inv[r] = 1.0f / rs[r];
    #pragma unroll
    for (int n = 0; n < 2; ++n)
        #pragma unroll
        for (int r = 0; r < 4; ++r) {
            int orow = b * NN + tile * 64 + w * 16 + g * 4 + r;
            o[(size_t)orow * CC + h * CHDIM + n * 16 + lr] = __float2bfloat16(oacc[n][r] * inv[r]);
        }
}

extern "C" void kernel_launch(void* const* d_in, const int* in_sizes, int n_in,
                              void* d_out, int out_size, void* d_ws, size_t ws_size,
                              hipStream_t stream) {
    const float* feat        = (const float*)d_in[0];
    const float* memory      = (const float*)d_in[1];
    const int*   member_idx  = (const int*)d_in[2];
    const int*   cluster_mask= (const int*)d_in[3];
    const int*   pe_idx     = (const int*)d_in[4];
    const float* pre_table   = (const float*)d_in[6];
    const float* Wq    = (const float*)d_in[7];
    const float* bq    = (const float*)d_in[8];
    const float* Wkv   = (const float*)d_in[9];
    const float* bkv   = (const float*)d_in[10];
    const float* blank_k = (const float*)d_in[11];
    const float* blank_v = (const float*)d_in[12];
    const float* Wpe   = (const float*)d_in[13];
    const float* bpe   = (const float*)d_in[14];
    const float* Wproj = (const float*)d_in[15];
    const float* bproj = (const float*)d_in[16];
    const float* g1    = (const float*)d_in[17];
    const float* be1   = (const float*)d_in[18];
    const float* g2    = (const float*)d_in[19];
    const float* be2   = (const float*)d_in[20];
    const float* xWq   = (const float*)d_in[21];
    const float* xbq   = (const float*)d_in[22];
    const float* xWk   = (const float*)d_in[23];
    const float* xbk   = (const float*)d_in[24];
    const float* xWv   = (const float*)d_in[25];
    const float* xbv   = (const float*)d_in[26];
    const float* xWo   = (const float*)d_in[27];
    const float* xbo   = (const float*)d_in[28];
    const float* xg    = (const float*)d_in[29];
    const float* xbe   = (const float*)d_in[30];
    const float* W1    = (const float*)d_in[31];
    const float* bf1   = (const float*)d_in[32];
    const float* W2    = (const float*)d_in[33];
    const float* bf2   = (const float*)d_in[34];
    float* out = (float*)d_out;
    float* ws  = (float*)d_ws;

    // workspace layout (float units)
    float* qkvF  = ws;                         // [8192][768] f32 (dead after cluster_attn)
    __hip_bfloat16* xqBf = (__hip_bfloat16*)ws; // alias: [8192][256] bf16
    float* xkvF  = ws + 2097152;               // [512][512] f32
    __hip_bfloat16* hBf  = (__hip_bfloat16*)(ws + 2359296);   // [8192][512] bf16
    float* feat1F = ws + 6291456;              // [8192][256] f32
    __hip_bfloat16* aBf  = (__hip_bfloat16*)(ws + 8388608);   // [8192][256] bf16 (LN outs)
    __hip_bfloat16* oBf  = (__hip_bfloat16*)(ws + 9437184);   // [8192][256] bf16 (attn outs)
    __hip_bfloat16* WqkvT = (__hip_bfloat16*)(ws + 10485760); // [768][256]
    __hip_bfloat16* WprojT= (__hip_bfloat16*)(ws + 10584064); // [256][256]
    __hip_bfloat16* xWqT  = (__hip_bfloat16*)(ws + 10616832);
    __hip_bfloat16* xWoT  = (__hip_bfloat16*)(ws + 10649600);
    __hip_bfloat16* xWkvT = (__hip_bfloat16*)(ws + 10682368); // [512][256]
    __hip_bfloat16* W1T   = (__hip_bfloat16*)(ws + 10747904); // [512][256]
    __hip_bfloat16* W2T   = (__hip_bfloat16*)(ws + 10813440); // [256][512]
    __hip_bfloat16* memBf = (__hip_bfloat16*)(ws + 10878976); // [512][256]
    float* pet   = ws + 10944512;              // 80000
    float* bqkv  = ws + 11024512;              // 768
    float* xbkv  = ws + 11025280;              // 512
    float* xbqS  = ws + 11025792;              // 256

    const float scale = 0.17677669529663689f; // 1/sqrt(32)

    // ---- prep ----
    pe_kernel<<<(TT * HH + 255) / 256, 256, 0, stream>>>(pre_table, Wpe, bpe, pet);
    WtArgs wa;
    wa.d[0] = { Wq,    WqkvT,          256, 256, 0,   scale };
    wa.d[1] = { Wkv,   WqkvT + 65536,  256, 512, 64,  1.0f };
    wa.d[2] = { Wproj, WprojT,         256, 256, 192, 1.0f };
    wa.d[3] = { xWq,   xWqT,           256, 256, 256, scale };
    wa.d[4] = { xWk,   xWkvT,          256, 256, 320, 1.0f };
    wa.d[5] = { xWv,   xWkvT + 65536,  256, 256, 384, 1.0f };
    wa.d[6] = { xWo,   xWoT,           256, 256, 448, 1.0f };
    wa.d[7] = { W1,    W1T,            256, 512, 512, 1.0f };
    wa.d[8] = { W2,    W2T,            512, 256, 640, 1.0f };
    wtrans_kernel<<<768, 256, 0, stream>>>(wa);
    bias_prep_kernel<<<6, 256, 0, stream>>>(bq, bkv, xbk, xbv, xbq, scale, bqkv, xbkv, xbqS);
    cvt_bf16_kernel<<<512, 256, 0, stream>>>(memory, memBf, 131072);

    // ---- block ----
    ln_kernel<<<ROWS, 256, 0, stream>>>(feat, g1, be1, aBf);
    mfma_gemm_kernel<0,0><<<dim3(12, 64), 256, 0, stream>>>(aBf, WqkvT, bqkv, qkvF, nullptr, ROWS, 768, 256);
    cluster_attn_kernel<<<ROWS * HH / 4, 256, 0, stream>>>(qkvF, member_idx, cluster_mask, pe_idx, pet, blank_k, blank_v, oBf);
    mfma_gemm_kernel<0,0><<<dim3(4, 64), 256, 0, stream>>>(oBf, WprojT, bproj, feat1F, feat, ROWS, 256, 256);
    ln_kernel<<<ROWS, 256, 0, stream>>>(feat1F, xg, xbe, aBf);
    mfma_gemm_kernel<0,1><<<dim3(4, 64), 256, 0, stream>>>(aBf, xWqT, xbqS, xqBf, nullptr, ROWS, 256, 256);
    mfma_gemm_kernel<0,0><<<dim3(8, 4), 256, 0, stream>>>(memBf, xWkvT, xbkv, xkvF, nullptr, 512, 512, 256);
    {
        size_t xlds = (256 * KSLD + 32 * PVLD + 4 * 16 * PVLD) * sizeof(short);
        cross_attn_kernel<<<dim3(NN / 64, HH, BB), 256, xlds, stream>>>(xqBf, xkvF, oBf);
    }
    mfma_gemm_kernel<0,0><<<dim3(4, 64), 256, 0, stream>>>(oBf, xWoT, xbo, out, feat1F, ROWS, 256, 256);
    ln_kernel<<<ROWS, 256, 0, stream>>>(out, g2, be2, aBf);
    mfma_gemm_kernel<1,1><<<dim3(8, 64), 256, 0, stream>>>(aBf, W1T, bf1, hBf, nullptr, ROWS, HIDD, 256);
    mfma_gemm_kernel<0,0><<<dim3(4, 64), 256, 0, stream>>>(hBf, W2T, bf2, out, out, ROWS, 256, HIDD);
}

// Round 6
// 192.499 us; speedup vs baseline: 3.5699x; 1.1368x over previous
//
#include <hip/hip_runtime.h>
#include <hip/hip_bf16.h>
#include <math.h>

// Problem constants
#define BB 2
#define NN 4096
#define CC 256
#define HH 8
#define MM 48
#define TT 10000
#define LL 256
#define CHDIM 32
#define HIDD 512
#define ROWS (BB*NN)   // 8192

typedef __attribute__((ext_vector_type(8))) short bf16x8;
typedef __attribute__((ext_vector_type(4))) float f32x4;

static __device__ __forceinline__ short f2bf(float x) {
    __hip_bfloat16 h = __float2bfloat16(x);
    return *reinterpret_cast<short*>(&h);
}
static __device__ __forceinline__ float bf2f(short s) {
    unsigned int u = ((unsigned int)(unsigned short)s) << 16;
    union { unsigned int u; float f; } c; c.u = u;
    return c.f;
}

// ---------------- pe_table = pre_table @ Wpe + bpe  (T x H) ----------------
__global__ void pe_kernel(const float* __restrict__ pre, const float* __restrict__ Wpe,
                          const float* __restrict__ bpe, float* __restrict__ pet) {
    int i = blockIdx.x * blockDim.x + threadIdx.x;   // t*H + h
    if (i >= TT * HH) return;
    int t = i / HH, h = i % HH;
    float s = bpe[h];
    #pragma unroll
    for (int j = 0; j < 5; ++j) s += pre[t * 5 + j] * Wpe[j * HH + h];
    pet[i] = s;
}

// ---------------- fused weight transpose+convert: dst[N][K] bf16 = src[K][N]*scl ----------------
struct WtDesc { const float* src; __hip_bfloat16* dst; int K; int N; int tile0; float scl; };
struct WtArgs { WtDesc d[9]; };
__global__ __launch_bounds__(256) void wtrans_kernel(WtArgs a) {
    __shared__ float tile[32][33];
    int bid = blockIdx.x;
    int mi = 0;
    #pragma unroll
    for (int i = 1; i < 9; ++i) if (bid >= a.d[i].tile0) mi = i;
    WtDesc dsc = a.d[mi];
    int t = bid - dsc.tile0;
    int tiles_n = dsc.N >> 5;
    int k0 = (t / tiles_n) * 32, n0 = (t % tiles_n) * 32;
    int tx = threadIdx.x & 31, ty = threadIdx.x >> 5;   // 32x8
    #pragma unroll
    for (int i = 0; i < 32; i += 8)
        tile[ty + i][tx] = dsc.src[(size_t)(k0 + ty + i) * dsc.N + n0 + tx];
    __syncthreads();
    #pragma unroll
    for (int i = 0; i < 32; i += 8)
        dsc.dst[(size_t)(n0 + ty + i) * dsc.K + k0 + tx] = __float2bfloat16(tile[tx][ty + i] * dsc.scl);
}

// ---------------- bias concat/scale prep ----------------
__global__ void bias_prep_kernel(const float* __restrict__ bq, const float* __restrict__ bkv,
                                 const float* __restrict__ xbk, const float* __restrict__ xbv,
                                 const float* __restrict__ xbq, float scale,
                                 float* __restrict__ bqkv, float* __restrict__ xbkv,
                                 float* __restrict__ xbqS) {
    int i = blockIdx.x * 256 + threadIdx.x;
    if (i < 256) bqkv[i] = bq[i] * scale;
    else if (i < 768) bqkv[i] = bkv[i - 256];
    else if (i < 1024) xbkv[i - 768] = xbk[i - 768];
    else if (i < 1280) xbkv[256 + i - 1024] = xbv[i - 1024];
    else if (i < 1536) xbqS[i - 1280] = xbq[i - 1280] * scale;
}

// ---------------- fp32 -> bf16 convert ----------------
__global__ void cvt_bf16_kernel(const float* __restrict__ src, __hip_bfloat16* __restrict__ dst, int n) {
    int i = blockIdx.x * 256 + threadIdx.x;
    if (i < n) dst[i] = __float2bfloat16(src[i]);
}

// ---------------- LayerNorm over C=256, one block per row, bf16 out ----------------
__global__ __launch_bounds__(256) void ln_kernel(const float* __restrict__ in,
                                                 const float* __restrict__ g,
                                                 const float* __restrict__ b,
                                                 __hip_bfloat16* __restrict__ out) {
    int row = blockIdx.x;
    int tid = threadIdx.x;
    float v = in[(size_t)row * CC + tid];
    __shared__ float r1[4], r2[4];
    float s = v;
    #pragma unroll
    for (int off = 32; off; off >>= 1) s += __shfl_xor(s, off, 64);
    if ((tid & 63) == 0) r1[tid >> 6] = s;
    __syncthreads();
    float mu = (r1[0] + r1[1] + r1[2] + r1[3]) * (1.0f / 256.0f);
    float d = v - mu;
    float s2 = d * d;
    #pragma unroll
    for (int off = 32; off; off >>= 1) s2 += __shfl_xor(s2, off, 64);
    if ((tid & 63) == 0) r2[tid >> 6] = s2;
    __syncthreads();
    float var = (r2[0] + r2[1] + r2[2] + r2[3]) * (1.0f / 256.0f);
    float rs = rsqrtf(var + 1e-5f);
    out[(size_t)row * CC + tid] = __float2bfloat16(d * rs * g[tid] + b[tid]);
}

// ---------------- MFMA bf16 GEMM: out = act(A@B^T + bias) + residual ----------------
#define GBM 128
#define GBN 64
#define GBK 64
#define LDA 72   // 64 + 8 pad (bf16 units)
template<int ACT, int OUTBF>
__global__ __launch_bounds__(256) void mfma_gemm_kernel(
    const __hip_bfloat16* __restrict__ A,
    const __hip_bfloat16* __restrict__ BT,
    const float* __restrict__ bias,
    void* __restrict__ outv,
    const float* __restrict__ residual,
    int M, int N, int K) {
    __shared__ short As[GBM * LDA];
    __shared__ short Bs[GBN * LDA];
    int tid = threadIdx.x;
    int lane = tid & 63, wid = tid >> 6;
    int wr = wid >> 1, wc = wid & 1;
    int row0 = blockIdx.y * GBM, col0 = blockIdx.x * GBN;
    int lr = lane & 15, lk = lane >> 4;
    f32x4 acc[4][2] = {};
    for (int kt = 0; kt < K; kt += GBK) {
        #pragma unroll
        for (int i = 0; i < 4; ++i) {
            int flat = tid + i * 256;
            int r = flat >> 3, kc = (flat & 7) * 8;
            *(bf16x8*)&As[r * LDA + kc] = *(const bf16x8*)(A + (size_t)(row0 + r) * K + kt + kc);
        }
        #pragma unroll
        for (int i = 0; i < 2; ++i) {
            int flat = tid + i * 256;
            int r = flat >> 3, kc = (flat & 7) * 8;
            *(bf16x8*)&Bs[r * LDA + kc] = *(const bf16x8*)(BT + (size_t)(col0 + r) * K + kt + kc);
        }
        __syncthreads();
        #pragma unroll
        for (int ks = 0; ks < 2; ++ks) {
            bf16x8 bfr[2];
            #pragma unroll
            for (int n = 0; n < 2; ++n)
                bfr[n] = *(const bf16x8*)&Bs[(wc * 32 + n * 16 + lr) * LDA + ks * 32 + lk * 8];
            #pragma unroll
            for (int m = 0; m < 4; ++m) {
                bf16x8 afr = *(const bf16x8*)&As[(wr * 64 + m * 16 + lr) * LDA + ks * 32 + lk * 8];
                #pragma unroll
                for (int n = 0; n < 2; ++n)
                    acc[m][n] = __builtin_amdgcn_mfma_f32_16x16x32_bf16(afr, bfr[n], acc[m][n], 0, 0, 0);
            }
        }
        __syncthreads();
    }
    float bv[2];
    #pragma unroll
    for (int n = 0; n < 2; ++n) bv[n] = bias[col0 + wc * 32 + n * 16 + lr];
    #pragma unroll
    for (int m = 0; m < 4; ++m) {
        #pragma unroll
        for (int n = 0; n < 2; ++n) {
            int col = col0 + wc * 32 + n * 16 + lr;
            #pragma unroll
            for (int r = 0; r < 4; ++r) {
                int row = row0 + wr * 64 + m * 16 + lk * 4 + r;
                float v = acc[m][n][r] + bv[n];
                if (ACT == 1) v = 0.5f * v * (1.0f + erff(v * 0.70710678118654752f));
                size_t oi = (size_t)row * N + col;
                if (residual) v += residual[oi];
                if (OUTBF) ((__hip_bfloat16*)outv)[oi] = __float2bfloat16(v);
                else ((float*)outv)[oi] = v;
            }
        }
    }
}

// ---------------- cluster attention v3: bf16 qkv gathers ----------------
// qkv bf16 [8192][768]: q at col h*32+c; k at 256+h*64+c; v at 256+h*64+32+c.
// Per head, K(64B)+V(64B) share one 128B line -> 2x gather line efficiency vs f32.
__global__ __launch_bounds__(256) void cluster_attn_kernel(
    const __hip_bfloat16* __restrict__ qkvh,
    const int* __restrict__ member_idx, const int* __restrict__ cluster_mask,
    const int* __restrict__ pe_idx, const float* __restrict__ pet,
    const float* __restrict__ blank_k, const float* __restrict__ blank_v,
    __hip_bfloat16* __restrict__ outp) {
    const short* qkv = (const short*)qkvh;
    __shared__ float s_q[4][32];
    int tid = threadIdx.x;
    int wid = tid >> 6, lane = tid & 63;
    int w = blockIdx.x * 4 + wid;      // (row*8 + h)
    int h = w & 7;
    int row = w >> 3;                  // b*4096 + n
    int b = row >> 12;
    if (lane < 32) s_q[wid][lane] = bf2f(qkv[(size_t)row * 768 + h * CHDIM + lane]);
    __syncthreads();

    int idxreg = 0;
    float e = 0.0f;
    if (lane < MM) {
        idxreg = member_idx[(size_t)row * MM + lane];
        const short* krow = qkv + ((size_t)(b * NN + idxreg)) * 768 + 256 + h * 64;
        float d = 0.0f;
        #pragma unroll
        for (int c8 = 0; c8 < 4; ++c8) {
            bf16x8 kk = *(const bf16x8*)(krow + c8 * 8);
            #pragma unroll
            for (int j = 0; j < 8; ++j) d += s_q[wid][c8 * 8 + j] * bf2f(kk[j]);
        }
        d += pet[(size_t)pe_idx[(size_t)row * MM + lane] * HH + h];
        if (cluster_mask[(size_t)row * MM + lane] == 0) d -= 100.0f;
        e = expf(d);   // logits O(1); no-max softmax, exp(-100)->0
    } else if (lane == MM) {
        const float4* bk4 = (const float4*)(blank_k + h * CHDIM);
        float d = 0.0f;
        #pragma unroll
        for (int c8 = 0; c8 < 8; ++c8) {
            float4 kk4 = bk4[c8];
            d += s_q[wid][c8 * 4 + 0] * kk4.x + s_q[wid][c8 * 4 + 1] * kk4.y
               + s_q[wid][c8 * 4 + 2] * kk4.z + s_q[wid][c8 * 4 + 3] * kk4.w;
        }
        e = expf(d);
    }
    float ssum = e;
    #pragma unroll
    for (int off = 32; off; off >>= 1) ssum += __shfl_xor(ssum, off, 64);
    float p = e / ssum;
    float p48 = __shfl(p, MM, 64);   // while all lanes active

    int c = lane & 31, half = lane >> 5;
    const short* vbase = qkv + 256 + h * 64 + 32 + c;
    float accv = 0.0f;
    int m0 = half * 24;
    #pragma unroll 8
    for (int m = m0; m < m0 + 24; ++m) {
        int im = __shfl(idxreg, m, 64);
        float pm = __shfl(p, m, 64);
        accv += pm * bf2f(vbase[(size_t)(b * NN + im) * 768]);
    }
    accv += __shfl_xor(accv, 32, 64);
    if (lane < 32) {
        accv += p48 * blank_v[h * CHDIM + c];
        outp[(size_t)row * CC + h * CHDIM + c] = __float2bfloat16(accv);
    }
}

// ---------------- cross attention v4.1: MFMA flash-style, bf16 K/V input ----------------
// Per block: one (b, h), 64 Q rows; 4 waves x 16 rows.
// LDS: Ks [256][40] bf16 | Vt [32][264] bf16 | Ps [4][16*264] bf16
#define KSLD 40
#define PVLD 264
__global__ __launch_bounds__(256) void cross_attn_kernel(
    const __hip_bfloat16* __restrict__ xq,   // [8192][256] bf16, scaled
    const __hip_bfloat16* __restrict__ xkvh, // [512][512] bf16: k at h*32+c, v at 256+h*32+c
    __hip_bfloat16* __restrict__ o) {
    const short* xkv = (const short*)xkvh;
    extern __shared__ short lds[];
    short* Ks = lds;                 // 256*40
    short* Vt = lds + 256 * KSLD;    // 32*264
    short* Ps = Vt + 32 * PVLD;      // 4*16*264
    int tid = threadIdx.x, lane = tid & 63, w = tid >> 6;
    int tile = blockIdx.x, h = blockIdx.y, b = blockIdx.z;
    int lr = lane & 15, g = lane >> 4;

    // stage K -> Ks[l][c], V -> Vt[c][l] (bf16 pass-through, no conversion)
    #pragma unroll
    for (int p = 0; p < 8; ++p) {
        int l = p * 32 + (tid >> 3);
        int c4 = (tid & 7) * 4;
        const short* kvrow = xkv + ((size_t)(b * LL + l)) * 512 + h * CHDIM;
        ushort4 kk = *(const ushort4*)(kvrow + c4);
        *(ushort4*)&Ks[l * KSLD + c4] = kk;
        ushort4 vv = *(const ushort4*)(kvrow + 256 + c4);
        Vt[(c4 + 0) * PVLD + l] = vv.x;
        Vt[(c4 + 1) * PVLD + l] = vv.y;
        Vt[(c4 + 2) * PVLD + l] = vv.z;
        Vt[(c4 + 3) * PVLD + l] = vv.w;
    }
    __syncthreads();

    // QK^T: S[16][256] per wave
    int qrow = b * NN + tile * 64 + w * 16 + lr;
    bf16x8 afr = *(const bf16x8*)(xq + (size_t)qrow * CC + h * CHDIM + g * 8);
    f32x4 s[16];
    #pragma unroll
    for (int t = 0; t < 16; ++t) {
        bf16x8 kb = *(const bf16x8*)&Ks[(t * 16 + lr) * KSLD + g * 8];
        s[t] = __builtin_amdgcn_mfma_f32_16x16x32_bf16(afr, kb, (f32x4){0.f,0.f,0.f,0.f}, 0, 0, 0);
    }
    // no-max softmax: exp + row sums (D row = g*4+r, col = t*16+lr)
    float rs[4] = {0.f, 0.f, 0.f, 0.f};
    #pragma unroll
    for (int t = 0; t < 16; ++t)
        #pragma unroll
        for (int r = 0; r < 4; ++r) { float e = __expf(s[t][r]); s[t][r] = e; rs[r] += e; }
    #pragma unroll
    for (int off = 1; off < 16; off <<= 1)
        #pragma unroll
        for (int r = 0; r < 4; ++r) rs[r] += __shfl_xor(rs[r], off, 64);
    short* Pw = Ps + w * 16 * PVLD;
    #pragma unroll
    for (int t = 0; t < 16; ++t)
        #pragma unroll
        for (int r = 0; r < 4; ++r)
            Pw[(g * 4 + r) * PVLD + t * 16 + lr] = f2bf(s[t][r]);
    // PV: out[16][32] = P @ V
    f32x4 oacc[2] = {};
    #pragma unroll
    for (int kc = 0; kc < 8; ++kc) {
        bf16x8 pa = *(const bf16x8*)&Pw[lr * PVLD + kc * 32 + g * 8];
        #pragma unroll
        for (int n = 0; n < 2; ++n) {
            bf16x8 vb = *(const bf16x8*)&Vt[(n * 16 + lr) * PVLD + kc * 32 + g * 8];
            oacc[n] = __builtin_amdgcn_mfma_f32_16x16x32_bf16(pa, vb, oacc[n], 0, 0, 0);
        }
    }
    float inv[4];
    #pragma unroll
    for (int r = 0; r < 4; ++r) inv[r] = 1.0f / rs[r];
    #pragma unroll
    for (int n = 0; n < 2; ++n)
        #pragma unroll
        for (int r = 0; r < 4; ++r) {
            int orow = b * NN + tile * 64 + w * 16 + g * 4 + r;
            o[(size_t)orow * CC + h * CHDIM + n * 16 + lr] = __float2bfloat16(oacc[n][r] * inv[r]);
        }
}

extern "C" void kernel_launch(void* const* d_in, const int* in_sizes, int n_in,
                              void* d_out, int out_size, void* d_ws, size_t ws_size,
                              hipStream_t stream) {
    const float* feat        = (const float*)d_in[0];
    const float* memory      = (const float*)d_in[1];
    const int*   member_idx  = (const int*)d_in[2];
    const int*   cluster_mask= (const int*)d_in[3];
    const int*   pe_idx      = (const int*)d_in[4];
    const float* pre_table   = (const float*)d_in[6];
    const float* Wq    = (const float*)d_in[7];
    const float* bq    = (const float*)d_in[8];
    const float* Wkv   = (const float*)d_in[9];
    const float* bkv   = (const float*)d_in[10];
    const float* blank_k = (const float*)d_in[11];
    const float* blank_v = (const float*)d_in[12];
    const float* Wpe   = (const float*)d_in[13];
    const float* bpe   = (const float*)d_in[14];
    const float* Wproj = (const float*)d_in[15];
    const float* bproj = (const float*)d_in[16];
    const float* g1    = (const float*)d_in[17];
    const float* be1   = (const float*)d_in[18];
    const float* g2    = (const float*)d_in[19];
    const float* be2   = (const float*)d_in[20];
    const float* xWq   = (const float*)d_in[21];
    const float* xbq   = (const float*)d_in[22];
    const float* xWk   = (const float*)d_in[23];
    const float* xbk   = (const float*)d_in[24];
    const float* xWv   = (const float*)d_in[25];
    const float* xbv   = (const float*)d_in[26];
    const float* xWo   = (const float*)d_in[27];
    const float* xbo   = (const float*)d_in[28];
    const float* xg    = (const float*)d_in[29];
    const float* xbe   = (const float*)d_in[30];
    const float* W1    = (const float*)d_in[31];
    const float* bf1   = (const float*)d_in[32];
    const float* W2    = (const float*)d_in[33];
    const float* bf2   = (const float*)d_in[34];
    float* out = (float*)d_out;
    float* ws  = (float*)d_ws;

    // workspace layout (float units)
    __hip_bfloat16* qkvBf = (__hip_bfloat16*)ws;              // [8192][768] bf16 (3,145,728 fl)
    __hip_bfloat16* xqBf  = (__hip_bfloat16*)ws;              // alias (qkv dead after cluster_attn)
    __hip_bfloat16* xkvBf = (__hip_bfloat16*)(ws + 3145728);  // [512][512] bf16 (131,072 fl)
    __hip_bfloat16* hBf   = (__hip_bfloat16*)(ws + 3276800);  // [8192][512] bf16 (2,097,152 fl)
    float* feat1F = ws + 5373952;                             // [8192][256] f32 (2,097,152 fl)
    __hip_bfloat16* aBf   = (__hip_bfloat16*)(ws + 7471104);  // [8192][256] bf16
    __hip_bfloat16* oBf   = (__hip_bfloat16*)(ws + 8519680);  // [8192][256] bf16
    __hip_bfloat16* WqkvT = (__hip_bfloat16*)(ws + 9568256);  // [768][256]
    __hip_bfloat16* WprojT= (__hip_bfloat16*)(ws + 9666560);  // [256][256]
    __hip_bfloat16* xWqT  = (__hip_bfloat16*)(ws + 9699328);
    __hip_bfloat16* xWoT  = (__hip_bfloat16*)(ws + 9732096);
    __hip_bfloat16* xWkvT = (__hip_bfloat16*)(ws + 9764864);  // [512][256]
    __hip_bfloat16* W1T   = (__hip_bfloat16*)(ws + 9830400);  // [512][256]
    __hip_bfloat16* W2T   = (__hip_bfloat16*)(ws + 9895936);  // [256][512]
    __hip_bfloat16* memBf = (__hip_bfloat16*)(ws + 9961472);  // [512][256]
    float* pet   = ws + 10027008;                             // 80000
    float* bqkv  = ws + 10107008;                             // 768
    float* xbkv  = ws + 10107776;                             // 512
    float* xbqS  = ws + 10108288;                             // 256

    const float scale = 0.17677669529663689f; // 1/sqrt(32)

    // ---- prep ----
    pe_kernel<<<(TT * HH + 255) / 256, 256, 0, stream>>>(pre_table, Wpe, bpe, pet);
    WtArgs wa;
    wa.d[0] = { Wq,    WqkvT,          256, 256, 0,   scale };
    wa.d[1] = { Wkv,   WqkvT + 65536,  256, 512, 64,  1.0f };
    wa.d[2] = { Wproj, WprojT,         256, 256, 192, 1.0f };
    wa.d[3] = { xWq,   xWqT,           256, 256, 256, scale };
    wa.d[4] = { xWk,   xWkvT,          256, 256, 320, 1.0f };
    wa.d[5] = { xWv,   xWkvT + 65536,  256, 256, 384, 1.0f };
    wa.d[6] = { xWo,   xWoT,           256, 256, 448, 1.0f };
    wa.d[7] = { W1,    W1T,            256, 512, 512, 1.0f };
    wa.d[8] = { W2,    W2T,            512, 256, 640, 1.0f };
    wtrans_kernel<<<768, 256, 0, stream>>>(wa);
    bias_prep_kernel<<<6, 256, 0, stream>>>(bq, bkv, xbk, xbv, xbq, scale, bqkv, xbkv, xbqS);
    cvt_bf16_kernel<<<512, 256, 0, stream>>>(memory, memBf, 131072);

    // ---- block ----
    ln_kernel<<<ROWS, 256, 0, stream>>>(feat, g1, be1, aBf);
    mfma_gemm_kernel<0,1><<<dim3(12, 64), 256, 0, stream>>>(aBf, WqkvT, bqkv, qkvBf, nullptr, ROWS, 768, 256);
    cluster_attn_kernel<<<ROWS * HH / 4, 256, 0, stream>>>(qkvBf, member_idx, cluster_mask, pe_idx, pet, blank_k, blank_v, oBf);
    mfma_gemm_kernel<0,0><<<dim3(4, 64), 256, 0, stream>>>(oBf, WprojT, bproj, feat1F, feat, ROWS, 256, 256);
    ln_kernel<<<ROWS, 256, 0, stream>>>(feat1F, xg, xbe, aBf);
    mfma_gemm_kernel<0,1><<<dim3(4, 64), 256, 0, stream>>>(aBf, xWqT, xbqS, xqBf, nullptr, ROWS, 256, 256);
    mfma_gemm_kernel<0,1><<<dim3(8, 4), 256, 0, stream>>>(memBf, xWkvT, xbkv, xkvBf, nullptr, 512, 512, 256);
    {
        size_t xlds = (256 * KSLD + 32 * PVLD + 4 * 16 * PVLD) * sizeof(short);
        cross_attn_kernel<<<dim3(NN / 64, HH, BB), 256, xlds, stream>>>(xqBf, xkvBf, oBf);
    }
    mfma_gemm_kernel<0,0><<<dim3(4, 64), 256, 0, stream>>>(oBf, xWoT, xbo, out, feat1F, ROWS, 256, 256);
    ln_kernel<<<ROWS, 256, 0, stream>>>(out, g2, be2, aBf);
    mfma_gemm_kernel<1,1><<<dim3(8, 64), 256, 0, stream>>>(aBf, W1T, bf1, hBf, nullptr, ROWS, HIDD, 256);
    mfma_gemm_kernel<0,0><<<dim3(4, 64), 256, 0, stream>>>(hBf, W2T, bf2, out, out, ROWS, 256, HIDD);
}